// Round 14
// baseline (110.493 us; speedup 1.0000x reference)
//
#include <hip/hip_runtime.h>

#define NPT   120000            // points per batch
#define NB    2                 // batches
#define NSEG  262144            // 512*512 pillars
#define NXg   512
#define NSEGT (NB * NSEG)       // 524288 total segments
#define NPTS  (NB * NPT)        // 240000 total points

typedef __attribute__((ext_vector_type(8))) short  bf16x8;
typedef __attribute__((ext_vector_type(4))) float  f32x4;

__device__ __forceinline__ unsigned short f2bf(float f) {
    unsigned u = __float_as_uint(f);
    return (unsigned short)((u + 0x7FFFu + ((u >> 16) & 1u)) >> 16);   // RNE
}

// ---------------------------------------------------------------------------
// K0: zero cnt + gpref (custom fill — rocclr fill ran at 18 GB/s for 2 MB)
//     + BN-fold layer-1 weights (transposed bf16) in the extra block.
// ---------------------------------------------------------------------------
__global__ __launch_bounds__(256) void k_init(unsigned int* __restrict__ cnt,
                                              const float* __restrict__ w1,
                                              const float* __restrict__ g1,
                                              const float* __restrict__ b1,
                                              const float* __restrict__ m1,
                                              const float* __restrict__ v1,
                                              unsigned short* __restrict__ wtbf,
                                              float* __restrict__ bias1f,
                                              unsigned int* __restrict__ gpref) {
    int t = threadIdx.x;
    if (blockIdx.x < 512) {
        int idx = blockIdx.x * 256 + t;          // 131072 uint4 = 2 MB
        ((uint4*)cnt)[idx] = make_uint4(0u, 0u, 0u, 0u);
        return;
    }
    // prep block
    #pragma unroll
    for (int i = 0; i < 16; ++i) {
        int idx = t + i * 256;                   // idx = c*64 + k
        int c = idx >> 6, k = idx & 63;
        float al = g1[c] * rsqrtf(v1[c] + 1e-3f);
        wtbf[idx] = f2bf(w1[k * 64 + c] * al);
    }
    if (t < 64) bias1f[t] = b1[t] - m1[t] * (g1[t] * rsqrtf(v1[t] + 1e-3f));
    gpref[t] = 0u;
    gpref[t + 256] = 0u;
}

// ---------------------------------------------------------------------------
// K1: pillar id -> count atomic + arrival rank
// ---------------------------------------------------------------------------
__global__ __launch_bounds__(256) void k_stats(const float* __restrict__ pts,
                                               unsigned int* __restrict__ cnt,
                                               unsigned int* __restrict__ rank) {
    int tid = blockIdx.x * 256 + threadIdx.x;
    if (tid >= NPTS) return;
    const float* p = pts + (size_t)tid * 3;
    float x = p[0], y = p[1];
    // EXACT reference arithmetic: floor((x - lo)/vs), IEEE fp32 divide
    int xi = (int)floorf((x - (-51.2f)) / 0.2f);
    int yi = (int)floorf((y - (-51.2f)) / 0.2f);
    xi = min(max(xi, 0), 511);
    yi = min(max(yi, 0), 511);
    int b = (tid >= NPT) ? 1 : 0;
    int gvid = b * NSEG + (yi * NXg + xi);
    rank[tid] = atomicAdd(&cnt[gvid], 1u);
}

// ---------------------------------------------------------------------------
// Scan: block-local exclusive offs; block total scatter-added into gpref[j]
// for all j > bid (exact integer adds -> deterministic; visibility via
// kernel boundary — NOT the R8/R9 threadfence/tick pattern).
// Consumers use offs[g] + gpref[g>>10].  scan2 dispatch eliminated.
// ---------------------------------------------------------------------------
__global__ __launch_bounds__(256) void k_scan1(const unsigned int* __restrict__ cnt,
                                               unsigned int* __restrict__ offs,
                                               unsigned int* __restrict__ gpref) {
    __shared__ unsigned int s[256];
    int t = threadIdx.x;
    size_t base = (size_t)blockIdx.x * 1024 + t * 4;
    uint4 c4 = *(const uint4*)(cnt + base);
    unsigned int tsum = c4.x + c4.y + c4.z + c4.w;
    s[t] = tsum;
    __syncthreads();
    for (int o = 1; o < 256; o <<= 1) {
        unsigned int v = (t >= o) ? s[t - o] : 0u;
        __syncthreads();
        s[t] += v;
        __syncthreads();
    }
    unsigned int pre = s[t] - tsum;          // exclusive within block
    uint4 o4;
    o4.x = pre; o4.y = pre + c4.x; o4.z = o4.y + c4.y; o4.w = o4.z + c4.z;
    *(uint4*)(offs + base) = o4;

    unsigned total = s[255];
    #pragma unroll
    for (int h = 0; h < 2; ++h) {
        int j = t + h * 256;
        if (j > (int)blockIdx.x) atomicAdd(&gpref[j], total);
    }
}

// ---------------------------------------------------------------------------
// K2: counting-sort apply. pos = offs[gvid] + gpref[g>>10] + rank.
//     comb packs (vid&63)<<18 | tid  (tid < 2^18).
// ---------------------------------------------------------------------------
__global__ __launch_bounds__(256) void k_reorder(const float* __restrict__ pts,
                                                 const unsigned int* __restrict__ rank,
                                                 const unsigned int* __restrict__ offs,
                                                 const unsigned int* __restrict__ gpref,
                                                 float4* __restrict__ sxyz,
                                                 unsigned int* __restrict__ comb) {
    int tid = blockIdx.x * 256 + threadIdx.x;
    if (tid >= NPTS) return;
    const float* p = pts + (size_t)tid * 3;
    float x = p[0], y = p[1], z = p[2];
    int xi = (int)floorf((x - (-51.2f)) / 0.2f);
    int yi = (int)floorf((y - (-51.2f)) / 0.2f);
    xi = min(max(xi, 0), 511);
    yi = min(max(yi, 0), 511);
    int b = (tid >= NPT) ? 1 : 0;
    int gvid = b * NSEG + (yi * NXg + xi);
    unsigned pos = offs[gvid] + gpref[gvid >> 10] + rank[tid];
    sxyz[pos] = make_float4(x, y, z, __int_as_float(gvid));
    comb[pos] = ((unsigned)(gvid & 63) << 18) | (unsigned)tid;
}

// ---------------------------------------------------------------------------
// K3: PFN layer0, position-parallel. Pillar mean from contiguous siblings
//     (sum only), then ONE 32-ch GEMV on self features. Pool lives in pfn1.
//     Writes the 64B bf16 own-row (4 uint4).
// ---------------------------------------------------------------------------
__global__ __launch_bounds__(256) void k_pfn0(const float4* __restrict__ sxyz,
                                              const unsigned int* __restrict__ offs,
                                              const unsigned int* __restrict__ gpref,
                                              const unsigned int* __restrict__ cnt,
                                              const float* __restrict__ w0,
                                              const float* __restrict__ g0,
                                              const float* __restrict__ b0,
                                              const float* __restrict__ m0,
                                              const float* __restrict__ v0,
                                              unsigned short* __restrict__ xbf) {
    __shared__ float w0f[256];   // BN-folded [8][32]
    __shared__ float bias0[32];
    int t = threadIdx.x;
    {
        int c = t & 31;
        float al = g0[c] * rsqrtf(v0[c] + 1e-3f);
        w0f[t] = w0[t] * al;
        if (t < 32) bias0[t] = b0[t] - m0[t] * al;
    }
    __syncthreads();

    int pos = blockIdx.x * 256 + t;
    if (pos >= NPTS) return;

    float4 me = sxyz[pos];
    float x = me.x, y = me.y, z = me.z;
    int gvid = __float_as_int(me.w);
    int vid = gvid & (NSEG - 1);
    int xi = vid & (NXg - 1), yi = vid >> 9;

    unsigned off = offs[gvid] + gpref[gvid >> 10];
    unsigned n   = cnt[gvid];               // >= 1
    float sx = 0.f, sy = 0.f, sz = 0.f;
    for (unsigned i = 0; i < n; ++i) {
        float4 q = sxyz[off + i];
        sx += q.x; sy += q.y; sz += q.z;
    }
    float inv = 1.0f / (float)n;
    float mx = sx * inv, my = sy * inv, mz = sz * inv;
    float cx = ((float)xi + 0.5f) * 0.2f + (-51.2f);
    float cy = ((float)yi + 0.5f) * 0.2f + (-51.2f);

    float f[8] = {x, y, z, x - mx, y - my, z - mz, x - cx, y - cy};

    unsigned wv[16];
    #pragma unroll
    for (int c2 = 0; c2 < 16; ++c2) {
        float a0 = bias0[2 * c2], a1 = bias0[2 * c2 + 1];
        #pragma unroll
        for (int k = 0; k < 8; ++k) {
            a0 += f[k] * w0f[k * 32 + 2 * c2];
            a1 += f[k] * w0f[k * 32 + 2 * c2 + 1];
        }
        wv[c2] = (unsigned)f2bf(fmaxf(a0, 0.0f)) |
                 ((unsigned)f2bf(fmaxf(a1, 0.0f)) << 16);
    }
    uint4* dst = (uint4*)(xbf + (size_t)pos * 32);
    dst[0] = make_uint4(wv[0],  wv[1],  wv[2],  wv[3]);
    dst[1] = make_uint4(wv[4],  wv[5],  wv[6],  wv[7]);
    dst[2] = make_uint4(wv[8],  wv[9],  wv[10], wv[11]);
    dst[3] = make_uint4(wv[12], wv[13], wv[14], wv[15]);
}

// ---------------------------------------------------------------------------
// K4 (fused MFMA): 64 pillars / 256-thread block (4 waves).
//   pre  : per-tile pooled max pl[64][32] (bf16) — thread=(pillar, 8ch).
//   stage: per-wave own-half from xbf + pool-half from pl[vloc].
//   MFMA : 16 points x 64 ch per wave; B-frag carries ch = (l&15)*4 + n so
//          each lane's 4 n-outputs are CONTIGUOUS channels -> float4 ptfeat
//          store. ptfeat/canvas use NON-TEMPORAL stores (write-once data,
//          keeps xbf/comb resident in L2).
//   tail : transposed float4 canvas write
// ---------------------------------------------------------------------------
__global__ __launch_bounds__(256) void k_pfn1(const unsigned short* __restrict__ xbf,
                                              const unsigned int* __restrict__ comb,
                                              const unsigned int* __restrict__ offs,
                                              const unsigned int* __restrict__ gpref,
                                              const unsigned int* __restrict__ cnt,
                                              const unsigned short* __restrict__ wtbf,
                                              const float* __restrict__ bias1f,
                                              float* __restrict__ ptfeat,
                                              float* __restrict__ canvas) {
    __shared__ unsigned short xlds[64 * 64]; // swizzled bf16 X rows (8KB)
    __shared__ unsigned voxl[64][65];        // fp32 bits, padded
    __shared__ unsigned combs[64];
    __shared__ unsigned short pl[64][32];    // pooled bf16 per pillar (4KB)
    __shared__ unsigned offl[64];
    __shared__ unsigned cntl[64];

    int t = threadIdx.x;
    int l = t & 63;                          // lane in wave
    int w = t >> 6;                          // wave 0..3

    int batch = blockIdx.x >> 12;            // 4096 blocks per batch
    int vid0 = (blockIdx.x & 4095) << 6;
    int gvid0 = batch * NSEG + vid0;

    #pragma unroll
    for (int i = 0; i < 17; ++i) {
        int idx = t + i * 256;
        if (idx < 64 * 65) ((unsigned*)voxl)[idx] = 0u;
    }
    if (t < 64) {
        int g = gvid0 + t;
        offl[t] = offs[g] + gpref[g >> 10];
        cntl[t] = cnt[g];
    }

    // B-fragments: lane holds WT[ch = (l&15)*4 + n][k = ks*32 + (l/16)*8 + e]
    bf16x8 bfr[4][2];
    float bia[4];
    #pragma unroll
    for (int n = 0; n < 4; ++n) {
        int ch = (l & 15) * 4 + n;
        #pragma unroll
        for (int ks = 0; ks < 2; ++ks)
            bfr[n][ks] = *(const bf16x8*)(wtbf + (ch * 64 +
                                                  ks * 32 + (l >> 4) * 8));
        bia[n] = bias1f[ch];
    }
    __syncthreads();                         // offl/cntl + voxl zero visible

    // ---- pool pre-pass: thread=(pillar v, 8-ch group j) ----
    {
        int v = t >> 2, j = t & 3;
        unsigned o = offl[v], n = cntl[v];
        float pf[8];
        #pragma unroll
        for (int e = 0; e < 8; ++e) pf[e] = 0.0f;
        for (unsigned i = 0; i < n; ++i) {
            bf16x8 r = *(const bf16x8*)(xbf + (size_t)(o + i) * 32 + j * 8);
            #pragma unroll
            for (int e = 0; e < 8; ++e)
                pf[e] = fmaxf(pf[e], __uint_as_float((unsigned)(unsigned short)r[e] << 16));
        }
        bf16x8 pb;
        #pragma unroll
        for (int e = 0; e < 8; ++e)
            pb[e] = (short)(unsigned short)(__float_as_uint(pf[e]) >> 16); // exact (already bf16)
        *(bf16x8*)&pl[v][j * 8] = pb;
    }
    __syncthreads();                         // pl ready

    unsigned poslo = offl[0];
    unsigned poshi = offl[63] + cntl[63];

    for (unsigned pc = poslo; pc < poshi; pc += 64) {
        unsigned m = min(64u, poshi - pc);

        if ((unsigned)(w * 16) < m) {
            // per-wave stage: own half — 16 rows x 4 segs, 1 per lane
            int pt = w * 16 + (l >> 2), seg = l & 3;
            unsigned sw = (unsigned)(pt & 7) << 4;
            if (pt < (int)m) {
                bf16x8 val = *(const bf16x8*)(xbf + (size_t)(pc + pt) * 32 + seg * 8);
                *(bf16x8*)((char*)xlds + ((unsigned)(pt * 128 + seg * 16) ^ sw)) = val;
            }
            if (l < 16 && (w * 16 + l) < (int)m)
                combs[w * 16 + l] = comb[pc + w * 16 + l];
            // pool half from pl[vloc] (combs written by this wave above)
            if (pt < (int)m) {
                unsigned vloc = combs[pt] >> 18;
                bf16x8 pv = *(const bf16x8*)&pl[vloc][seg * 8];
                *(bf16x8*)((char*)xlds + ((unsigned)(pt * 128 + 64 + seg * 16) ^ sw)) = pv;
            }

            // MFMA: 16 points x 64 channels (intra-wave lgkmcnt dependency)
            int row = w * 16 + (l & 15);
            unsigned base = (unsigned)(row * 128 + ((l >> 4) << 4));
            unsigned sw2 = (unsigned)(row & 7) << 4;
            bf16x8 a0 = *(const bf16x8*)((char*)xlds + ((base + 0) ^ sw2));
            bf16x8 a1 = *(const bf16x8*)((char*)xlds + ((base + 64) ^ sw2));
            f32x4 acc[4];
            #pragma unroll
            for (int n = 0; n < 4; ++n) {
                f32x4 a = {0.f, 0.f, 0.f, 0.f};
                a = __builtin_amdgcn_mfma_f32_16x16x32_bf16(a0, bfr[n][0], a, 0, 0, 0);
                a = __builtin_amdgcn_mfma_f32_16x16x32_bf16(a1, bfr[n][1], a, 0, 0, 0);
                acc[n] = a;
            }
            int cb = (l & 15) * 4;
            #pragma unroll
            for (int r = 0; r < 4; ++r) {
                int pidx = w * 16 + (l >> 4) * 4 + r;   // C: row=(l>>4)*4+r
                if (pidx < (int)m) {
                    unsigned u = combs[pidx];
                    f32x4 v4;
                    v4[0] = fmaxf(acc[0][r] + bia[0], 0.0f);
                    v4[1] = fmaxf(acc[1][r] + bia[1], 0.0f);
                    v4[2] = fmaxf(acc[2][r] + bia[2], 0.0f);
                    v4[3] = fmaxf(acc[3][r] + bia[3], 0.0f);
                    __builtin_nontemporal_store(v4,
                        (f32x4*)(ptfeat + (size_t)(u & 0x3FFFFu) * 64 + cb));
                    unsigned vloc = u >> 18;
                    atomicMax(&voxl[vloc][cb + 0], __float_as_uint(v4[0]));
                    atomicMax(&voxl[vloc][cb + 1], __float_as_uint(v4[1]));
                    atomicMax(&voxl[vloc][cb + 2], __float_as_uint(v4[2]));
                    atomicMax(&voxl[vloc][cb + 3], __float_as_uint(v4[3]));
                }
            }
        }
    }
    __syncthreads();                         // all voxl atomics done

    // transposed canvas write, nontemporal float4 along the pillar axis
    {
        float* cv = canvas + (size_t)batch * 64 * NSEG + vid0;
        int p0 = (t & 15) * 4;
        #pragma unroll
        for (int i = 0; i < 4; ++i) {
            int c = (t >> 4) + i * 16;
            f32x4 v4;
            v4[0] = __uint_as_float(voxl[p0 + 0][c]);
            v4[1] = __uint_as_float(voxl[p0 + 1][c]);
            v4[2] = __uint_as_float(voxl[p0 + 2][c]);
            v4[3] = __uint_as_float(voxl[p0 + 3][c]);
            __builtin_nontemporal_store(v4, (f32x4*)(cv + (size_t)c * NSEG + p0));
        }
    }
}

// ---------------------------------------------------------------------------
extern "C" void kernel_launch(void* const* d_in, const int* in_sizes, int n_in,
                              void* d_out, int out_size, void* d_ws, size_t ws_size,
                              hipStream_t stream) {
    const float* pts = (const float*)d_in[0];
    const float* w0  = (const float*)d_in[1];
    const float* g0  = (const float*)d_in[2];
    const float* b0  = (const float*)d_in[3];
    const float* m0  = (const float*)d_in[4];
    const float* v0  = (const float*)d_in[5];
    const float* w1  = (const float*)d_in[6];
    const float* g1  = (const float*)d_in[7];
    const float* b1  = (const float*)d_in[8];
    const float* m1  = (const float*)d_in[9];
    const float* v1  = (const float*)d_in[10];
    float* out = (float*)d_out;
    float* ptfeat = out + (size_t)NB * 64 * NSEG;   // point_feats after canvases

    // workspace layout (~26 MB)
    char* ws = (char*)d_ws;
    size_t off = 0;
    unsigned int* cnt   = (unsigned int*)(ws + off); off += (size_t)NSEGT * 4;
    unsigned int* offs  = (unsigned int*)(ws + off); off += (size_t)NSEGT * 4;
    unsigned int* rank  = (unsigned int*)(ws + off); off += (size_t)NPTS * 4;
    unsigned int* comb  = (unsigned int*)(ws + off); off += (size_t)NPTS * 4;
    float4* sxyz        = (float4*)(ws + off);       off += (size_t)NPTS * 16;
    unsigned short* xbf = (unsigned short*)(ws + off); off += (size_t)NPTS * 32 * 2;
    unsigned short* wtbf= (unsigned short*)(ws + off); off += 4096 * 2;
    float* bias1f       = (float*)(ws + off);        off += 64 * 4;
    unsigned int* gpref = (unsigned int*)(ws + off); off += 512 * 4;

    int nblk = (NPTS + 255) / 256;
    k_init<<<513, 256, 0, stream>>>(cnt, w1, g1, b1, m1, v1, wtbf, bias1f, gpref);
    k_stats<<<nblk, 256, 0, stream>>>(pts, cnt, rank);
    k_scan1<<<NSEGT / 1024, 256, 0, stream>>>(cnt, offs, gpref);
    k_reorder<<<nblk, 256, 0, stream>>>(pts, rank, offs, gpref, sxyz, comb);
    k_pfn0<<<nblk, 256, 0, stream>>>(sxyz, offs, gpref, cnt,
                                     w0, g0, b0, m0, v0, xbf);
    k_pfn1<<<NB * 4096, 256, 0, stream>>>(xbf, comb, offs, gpref, cnt,
                                          wtbf, bias1f, ptfeat, out);
}

// Round 15
// 103.688 us; speedup vs baseline: 1.0656x; 1.0656x over previous
//
#include <hip/hip_runtime.h>

#define NPT   120000            // points per batch
#define NB    2                 // batches
#define NSEG  262144            // 512*512 pillars
#define NXg   512
#define NSEGT (NB * NSEG)       // 524288 total segments
#define NPTS  (NB * NPT)        // 240000 total points

typedef __attribute__((ext_vector_type(8))) short  bf16x8;
typedef __attribute__((ext_vector_type(4))) float  f32x4;

__device__ __forceinline__ unsigned short f2bf(float f) {
    unsigned u = __float_as_uint(f);
    return (unsigned short)((u + 0x7FFFu + ((u >> 16) & 1u)) >> 16);   // RNE
}

// ---------------------------------------------------------------------------
// K0: zero cnt (custom fill — rocclr fill ran at 18 GB/s for 2 MB)
//     + BN-fold layer-1 weights (transposed bf16) in the extra block.
// ---------------------------------------------------------------------------
__global__ __launch_bounds__(256) void k_init(unsigned int* __restrict__ cnt,
                                              const float* __restrict__ w1,
                                              const float* __restrict__ g1,
                                              const float* __restrict__ b1,
                                              const float* __restrict__ m1,
                                              const float* __restrict__ v1,
                                              unsigned short* __restrict__ wtbf,
                                              float* __restrict__ bias1f) {
    int t = threadIdx.x;
    if (blockIdx.x < 512) {
        int idx = blockIdx.x * 256 + t;          // 131072 uint4 = 2 MB
        ((uint4*)cnt)[idx] = make_uint4(0u, 0u, 0u, 0u);
        return;
    }
    // prep block
    #pragma unroll
    for (int i = 0; i < 16; ++i) {
        int idx = t + i * 256;                   // idx = c*64 + k
        int c = idx >> 6, k = idx & 63;
        float al = g1[c] * rsqrtf(v1[c] + 1e-3f);
        wtbf[idx] = f2bf(w1[k * 64 + c] * al);
    }
    if (t < 64) bias1f[t] = b1[t] - m1[t] * (g1[t] * rsqrtf(v1[t] + 1e-3f));
}

// ---------------------------------------------------------------------------
// K1: pillar id -> count atomic + arrival rank
// ---------------------------------------------------------------------------
__global__ __launch_bounds__(256) void k_stats(const float* __restrict__ pts,
                                               unsigned int* __restrict__ cnt,
                                               unsigned int* __restrict__ rank) {
    int tid = blockIdx.x * 256 + threadIdx.x;
    if (tid >= NPTS) return;
    const float* p = pts + (size_t)tid * 3;
    float x = p[0], y = p[1];
    // EXACT reference arithmetic: floor((x - lo)/vs), IEEE fp32 divide
    int xi = (int)floorf((x - (-51.2f)) / 0.2f);
    int yi = (int)floorf((y - (-51.2f)) / 0.2f);
    xi = min(max(xi, 0), 511);
    yi = min(max(yi, 0), 511);
    int b = (tid >= NPT) ? 1 : 0;
    int gvid = b * NSEG + (yi * NXg + xi);
    rank[tid] = atomicAdd(&cnt[gvid], 1u);
}

// ---------------------------------------------------------------------------
// Prefix scan of cnt[524288]: block-local offs + bsum, then scan bsum.
// Consumers add bsum[g>>10].
// (R8/R9: tick-fused scan with per-block threadfence regressed ~50 µs.
//  R14: scatter-add gpref fusion + NT stores regressed ~7 µs. Keep separate.)
// ---------------------------------------------------------------------------
__global__ __launch_bounds__(256) void k_scan1(const unsigned int* __restrict__ cnt,
                                               unsigned int* __restrict__ offs,
                                               unsigned int* __restrict__ bsum) {
    __shared__ unsigned int s[256];
    int t = threadIdx.x;
    size_t base = (size_t)blockIdx.x * 1024 + t * 4;
    uint4 c4 = *(const uint4*)(cnt + base);
    unsigned int tsum = c4.x + c4.y + c4.z + c4.w;
    s[t] = tsum;
    __syncthreads();
    for (int o = 1; o < 256; o <<= 1) {
        unsigned int v = (t >= o) ? s[t - o] : 0u;
        __syncthreads();
        s[t] += v;
        __syncthreads();
    }
    unsigned int pre = s[t] - tsum;          // exclusive within block
    if (t == 255) bsum[blockIdx.x] = s[255];
    uint4 o4;
    o4.x = pre; o4.y = pre + c4.x; o4.z = o4.y + c4.y; o4.w = o4.z + c4.z;
    *(uint4*)(offs + base) = o4;
}

__global__ __launch_bounds__(256) void k_scan2(unsigned int* __restrict__ bsum) {
    __shared__ unsigned int s[256];
    int t = threadIdx.x;
    unsigned int a = bsum[2 * t], b = bsum[2 * t + 1];
    unsigned int ts = a + b;
    s[t] = ts;
    __syncthreads();
    for (int o = 1; o < 256; o <<= 1) {
        unsigned int v = (t >= o) ? s[t - o] : 0u;
        __syncthreads();
        s[t] += v;
        __syncthreads();
    }
    unsigned int pre = s[t] - ts;
    bsum[2 * t] = pre;
    bsum[2 * t + 1] = pre + a;
}

// ---------------------------------------------------------------------------
// K2: counting-sort apply. pos = offs[gvid] + bsum[g>>10] + rank.
//     comb packs (vid&63)<<18 | tid  (tid < 2^18).
// ---------------------------------------------------------------------------
__global__ __launch_bounds__(256) void k_reorder(const float* __restrict__ pts,
                                                 const unsigned int* __restrict__ rank,
                                                 const unsigned int* __restrict__ offs,
                                                 const unsigned int* __restrict__ bsum,
                                                 float4* __restrict__ sxyz,
                                                 unsigned int* __restrict__ comb) {
    int tid = blockIdx.x * 256 + threadIdx.x;
    if (tid >= NPTS) return;
    const float* p = pts + (size_t)tid * 3;
    float x = p[0], y = p[1], z = p[2];
    int xi = (int)floorf((x - (-51.2f)) / 0.2f);
    int yi = (int)floorf((y - (-51.2f)) / 0.2f);
    xi = min(max(xi, 0), 511);
    yi = min(max(yi, 0), 511);
    int b = (tid >= NPT) ? 1 : 0;
    int gvid = b * NSEG + (yi * NXg + xi);
    unsigned pos = offs[gvid] + bsum[gvid >> 10] + rank[tid];
    sxyz[pos] = make_float4(x, y, z, __int_as_float(gvid));
    comb[pos] = ((unsigned)(gvid & 63) << 18) | (unsigned)tid;
}

// ---------------------------------------------------------------------------
// K3: PFN layer0, position-parallel. Pillar mean from contiguous siblings
//     (sum only), then ONE 32-ch GEMV on self features. Pool lives in pfn1.
//     Writes the 64B bf16 own-row (4 uint4).
// ---------------------------------------------------------------------------
__global__ __launch_bounds__(256) void k_pfn0(const float4* __restrict__ sxyz,
                                              const unsigned int* __restrict__ offs,
                                              const unsigned int* __restrict__ bsum,
                                              const unsigned int* __restrict__ cnt,
                                              const float* __restrict__ w0,
                                              const float* __restrict__ g0,
                                              const float* __restrict__ b0,
                                              const float* __restrict__ m0,
                                              const float* __restrict__ v0,
                                              unsigned short* __restrict__ xbf) {
    __shared__ float w0f[256];   // BN-folded [8][32]
    __shared__ float bias0[32];
    int t = threadIdx.x;
    {
        int c = t & 31;
        float al = g0[c] * rsqrtf(v0[c] + 1e-3f);
        w0f[t] = w0[t] * al;
        if (t < 32) bias0[t] = b0[t] - m0[t] * al;
    }
    __syncthreads();

    int pos = blockIdx.x * 256 + t;
    if (pos >= NPTS) return;

    float4 me = sxyz[pos];
    float x = me.x, y = me.y, z = me.z;
    int gvid = __float_as_int(me.w);
    int vid = gvid & (NSEG - 1);
    int xi = vid & (NXg - 1), yi = vid >> 9;

    unsigned off = offs[gvid] + bsum[gvid >> 10];
    unsigned n   = cnt[gvid];               // >= 1
    float sx = 0.f, sy = 0.f, sz = 0.f;
    for (unsigned i = 0; i < n; ++i) {
        float4 q = sxyz[off + i];
        sx += q.x; sy += q.y; sz += q.z;
    }
    float inv = 1.0f / (float)n;
    float mx = sx * inv, my = sy * inv, mz = sz * inv;
    float cx = ((float)xi + 0.5f) * 0.2f + (-51.2f);
    float cy = ((float)yi + 0.5f) * 0.2f + (-51.2f);

    float f[8] = {x, y, z, x - mx, y - my, z - mz, x - cx, y - cy};

    unsigned wv[16];
    #pragma unroll
    for (int c2 = 0; c2 < 16; ++c2) {
        float a0 = bias0[2 * c2], a1 = bias0[2 * c2 + 1];
        #pragma unroll
        for (int k = 0; k < 8; ++k) {
            a0 += f[k] * w0f[k * 32 + 2 * c2];
            a1 += f[k] * w0f[k * 32 + 2 * c2 + 1];
        }
        wv[c2] = (unsigned)f2bf(fmaxf(a0, 0.0f)) |
                 ((unsigned)f2bf(fmaxf(a1, 0.0f)) << 16);
    }
    uint4* dst = (uint4*)(xbf + (size_t)pos * 32);
    dst[0] = make_uint4(wv[0],  wv[1],  wv[2],  wv[3]);
    dst[1] = make_uint4(wv[4],  wv[5],  wv[6],  wv[7]);
    dst[2] = make_uint4(wv[8],  wv[9],  wv[10], wv[11]);
    dst[3] = make_uint4(wv[12], wv[13], wv[14], wv[15]);
}

// ---------------------------------------------------------------------------
// K4 (fused MFMA): 64 pillars / 256-thread block (4 waves).
//   pre  : per-tile pooled max pl[64][32] (bf16) — thread=(pillar, 8ch).
//   stage: per-wave own-half from xbf + pool-half from pl[vloc].
//   MFMA : 16 points x 64 ch per wave; B-frag carries ch = (l&15)*4 + n so
//          each lane's 4 n-outputs are CONTIGUOUS channels -> float4 ptfeat
//          store (one 256B burst per point row per lane group).
//   tail : transposed float4 canvas write
// ---------------------------------------------------------------------------
__global__ __launch_bounds__(256) void k_pfn1(const unsigned short* __restrict__ xbf,
                                              const unsigned int* __restrict__ comb,
                                              const unsigned int* __restrict__ offs,
                                              const unsigned int* __restrict__ bsum,
                                              const unsigned int* __restrict__ cnt,
                                              const unsigned short* __restrict__ wtbf,
                                              const float* __restrict__ bias1f,
                                              float* __restrict__ ptfeat,
                                              float* __restrict__ canvas) {
    __shared__ unsigned short xlds[64 * 64]; // swizzled bf16 X rows (8KB)
    __shared__ unsigned voxl[64][65];        // fp32 bits, padded
    __shared__ unsigned combs[64];
    __shared__ unsigned short pl[64][32];    // pooled bf16 per pillar (4KB)
    __shared__ unsigned offl[64];
    __shared__ unsigned cntl[64];

    int t = threadIdx.x;
    int l = t & 63;                          // lane in wave
    int w = t >> 6;                          // wave 0..3

    int batch = blockIdx.x >> 12;            // 4096 blocks per batch
    int vid0 = (blockIdx.x & 4095) << 6;
    int gvid0 = batch * NSEG + vid0;

    #pragma unroll
    for (int i = 0; i < 17; ++i) {
        int idx = t + i * 256;
        if (idx < 64 * 65) ((unsigned*)voxl)[idx] = 0u;
    }
    if (t < 64) {
        int g = gvid0 + t;
        offl[t] = offs[g] + bsum[g >> 10];
        cntl[t] = cnt[g];
    }

    // B-fragments: lane holds WT[ch = (l&15)*4 + n][k = ks*32 + (l/16)*8 + e]
    // (channel permutation so a lane's 4 n-outputs are contiguous channels)
    bf16x8 bfr[4][2];
    float bia[4];
    #pragma unroll
    for (int n = 0; n < 4; ++n) {
        int ch = (l & 15) * 4 + n;
        #pragma unroll
        for (int ks = 0; ks < 2; ++ks)
            bfr[n][ks] = *(const bf16x8*)(wtbf + (ch * 64 +
                                                  ks * 32 + (l >> 4) * 8));
        bia[n] = bias1f[ch];
    }
    __syncthreads();                         // offl/cntl + voxl zero visible

    // ---- pool pre-pass: thread=(pillar v, 8-ch group j) ----
    {
        int v = t >> 2, j = t & 3;
        unsigned o = offl[v], n = cntl[v];
        float pf[8];
        #pragma unroll
        for (int e = 0; e < 8; ++e) pf[e] = 0.0f;
        for (unsigned i = 0; i < n; ++i) {
            bf16x8 r = *(const bf16x8*)(xbf + (size_t)(o + i) * 32 + j * 8);
            #pragma unroll
            for (int e = 0; e < 8; ++e)
                pf[e] = fmaxf(pf[e], __uint_as_float((unsigned)(unsigned short)r[e] << 16));
        }
        bf16x8 pb;
        #pragma unroll
        for (int e = 0; e < 8; ++e)
            pb[e] = (short)(unsigned short)(__float_as_uint(pf[e]) >> 16); // exact (already bf16)
        *(bf16x8*)&pl[v][j * 8] = pb;
    }
    __syncthreads();                         // pl ready

    unsigned poslo = offl[0];
    unsigned poshi = offl[63] + cntl[63];

    for (unsigned pc = poslo; pc < poshi; pc += 64) {
        unsigned m = min(64u, poshi - pc);

        if ((unsigned)(w * 16) < m) {
            // per-wave stage: own half — 16 rows x 4 segs, 1 per lane
            int pt = w * 16 + (l >> 2), seg = l & 3;
            unsigned sw = (unsigned)(pt & 7) << 4;
            if (pt < (int)m) {
                bf16x8 val = *(const bf16x8*)(xbf + (size_t)(pc + pt) * 32 + seg * 8);
                *(bf16x8*)((char*)xlds + ((unsigned)(pt * 128 + seg * 16) ^ sw)) = val;
            }
            if (l < 16 && (w * 16 + l) < (int)m)
                combs[w * 16 + l] = comb[pc + w * 16 + l];
            // pool half from pl[vloc] (combs written by this wave above)
            if (pt < (int)m) {
                unsigned vloc = combs[pt] >> 18;
                bf16x8 pv = *(const bf16x8*)&pl[vloc][seg * 8];
                *(bf16x8*)((char*)xlds + ((unsigned)(pt * 128 + 64 + seg * 16) ^ sw)) = pv;
            }

            // MFMA: 16 points x 64 channels (intra-wave lgkmcnt dependency)
            int row = w * 16 + (l & 15);
            unsigned base = (unsigned)(row * 128 + ((l >> 4) << 4));
            unsigned sw2 = (unsigned)(row & 7) << 4;
            bf16x8 a0 = *(const bf16x8*)((char*)xlds + ((base + 0) ^ sw2));
            bf16x8 a1 = *(const bf16x8*)((char*)xlds + ((base + 64) ^ sw2));
            f32x4 acc[4];
            #pragma unroll
            for (int n = 0; n < 4; ++n) {
                f32x4 a = {0.f, 0.f, 0.f, 0.f};
                a = __builtin_amdgcn_mfma_f32_16x16x32_bf16(a0, bfr[n][0], a, 0, 0, 0);
                a = __builtin_amdgcn_mfma_f32_16x16x32_bf16(a1, bfr[n][1], a, 0, 0, 0);
                acc[n] = a;
            }
            int cb = (l & 15) * 4;
            #pragma unroll
            for (int r = 0; r < 4; ++r) {
                int pidx = w * 16 + (l >> 4) * 4 + r;   // C: row=(l>>4)*4+r
                if (pidx < (int)m) {
                    unsigned u = combs[pidx];
                    float4 v4;
                    v4.x = fmaxf(acc[0][r] + bia[0], 0.0f);
                    v4.y = fmaxf(acc[1][r] + bia[1], 0.0f);
                    v4.z = fmaxf(acc[2][r] + bia[2], 0.0f);
                    v4.w = fmaxf(acc[3][r] + bia[3], 0.0f);
                    *(float4*)(ptfeat + (size_t)(u & 0x3FFFFu) * 64 + cb) = v4;
                    unsigned vloc = u >> 18;
                    atomicMax(&voxl[vloc][cb + 0], __float_as_uint(v4.x));
                    atomicMax(&voxl[vloc][cb + 1], __float_as_uint(v4.y));
                    atomicMax(&voxl[vloc][cb + 2], __float_as_uint(v4.z));
                    atomicMax(&voxl[vloc][cb + 3], __float_as_uint(v4.w));
                }
            }
        }
    }
    __syncthreads();                         // all voxl atomics done

    // transposed canvas write, float4 along the pillar axis
    {
        float* cv = canvas + (size_t)batch * 64 * NSEG + vid0;
        int p0 = (t & 15) * 4;
        #pragma unroll
        for (int i = 0; i < 4; ++i) {
            int c = (t >> 4) + i * 16;
            float4 v4 = make_float4(__uint_as_float(voxl[p0 + 0][c]),
                                    __uint_as_float(voxl[p0 + 1][c]),
                                    __uint_as_float(voxl[p0 + 2][c]),
                                    __uint_as_float(voxl[p0 + 3][c]));
            *(float4*)(cv + (size_t)c * NSEG + p0) = v4;
        }
    }
}

// ---------------------------------------------------------------------------
extern "C" void kernel_launch(void* const* d_in, const int* in_sizes, int n_in,
                              void* d_out, int out_size, void* d_ws, size_t ws_size,
                              hipStream_t stream) {
    const float* pts = (const float*)d_in[0];
    const float* w0  = (const float*)d_in[1];
    const float* g0  = (const float*)d_in[2];
    const float* b0  = (const float*)d_in[3];
    const float* m0  = (const float*)d_in[4];
    const float* v0  = (const float*)d_in[5];
    const float* w1  = (const float*)d_in[6];
    const float* g1  = (const float*)d_in[7];
    const float* b1  = (const float*)d_in[8];
    const float* m1  = (const float*)d_in[9];
    const float* v1  = (const float*)d_in[10];
    float* out = (float*)d_out;
    float* ptfeat = out + (size_t)NB * 64 * NSEG;   // point_feats after canvases

    // workspace layout (~26 MB)
    char* ws = (char*)d_ws;
    size_t off = 0;
    unsigned int* cnt   = (unsigned int*)(ws + off); off += (size_t)NSEGT * 4;
    unsigned int* offs  = (unsigned int*)(ws + off); off += (size_t)NSEGT * 4;
    unsigned int* rank  = (unsigned int*)(ws + off); off += (size_t)NPTS * 4;
    unsigned int* comb  = (unsigned int*)(ws + off); off += (size_t)NPTS * 4;
    float4* sxyz        = (float4*)(ws + off);       off += (size_t)NPTS * 16;
    unsigned short* xbf = (unsigned short*)(ws + off); off += (size_t)NPTS * 32 * 2;
    unsigned short* wtbf= (unsigned short*)(ws + off); off += 4096 * 2;
    float* bias1f       = (float*)(ws + off);        off += 64 * 4;
    unsigned int* bsum  = (unsigned int*)(ws + off); off += 512 * 4;

    int nblk = (NPTS + 255) / 256;
    k_init<<<513, 256, 0, stream>>>(cnt, w1, g1, b1, m1, v1, wtbf, bias1f);
    k_stats<<<nblk, 256, 0, stream>>>(pts, cnt, rank);
    k_scan1<<<NSEGT / 1024, 256, 0, stream>>>(cnt, offs, bsum);
    k_scan2<<<1, 256, 0, stream>>>(bsum);
    k_reorder<<<nblk, 256, 0, stream>>>(pts, rank, offs, bsum, sxyz, comb);
    k_pfn0<<<nblk, 256, 0, stream>>>(sxyz, offs, bsum, cnt,
                                     w0, g0, b0, m0, v0, xbf);
    k_pfn1<<<NB * 4096, 256, 0, stream>>>(xbf, comb, offs, bsum, cnt,
                                          wtbf, bias1f, ptfeat, out);
}